// Round 13
// baseline (3735.717 us; speedup 1.0000x reference)
//
#include <hip/hip_runtime.h>
#include <stdint.h>

// GRU encoder: B=64 T=512 U=E=1024 V=32000, gates z|r|h, reset_after=True.
// Round-19 structure:
//   Phase 0: init_h  — pack hidden -> tagged h32 planes (tag0 | int16@2^15);
//            buf1 pre-filled with sentinel tag 0xFFFF.
//   Phase 1: gemm_xp — r16 1-term bf16 gather GEMM (proven, absmax-neutral).
//   Phase 2: gru_scan — 256 WGs x 512 thr, r16 grid/data layout, but the
//     ENTIRE barrier apparatus (h-store drain + flag store + wave-0 poll +
//     pre-poll + release sync) is replaced by SELF-CERTIFYING DATA:
//     h word = (step_tag<<16)|int16_h. Consumers load A speculatively and
//     check the 32 embedded tags per wave; stale -> retry (load IS the
//     poll; zero extra traffic when data is ready). Producer epilogue is
//     fire-and-forget. WAR-safe with 2 buffers by the same induction as
//     the proven flag protocol (publish t+1 requires consuming t for all
//     columns => all group WGs published t => all consumed t-1).
//     part[] double-buffered (48KB) -> ONE syncthreads/step; waves 4-7
//     run ahead into t+1 loads while waves 0-3 do the epilogue.
//     r18 post-mortem: XCD rendezvous machinery = coupled livelock modes,
//     crashed; abandoned. This keeps r16's proven residency (1 WG/CU).
//     Retry has spin budget: bail -> visible absmax fail, never a hang.
// ws: xp 201.33MB | h32 2x256KB = 201.85MB.

#define B_SZ   64
#define T_LEN  512
#define U_DIM  1024
#define E_DIM  1024
#define G3     3072
#define BU     (B_SZ * U_DIM)
#define XP_SCALE 131072.0f
#define XP_INV   (1.0f / 131072.0f)
#define H_SCALE  32768.0f
#define H_INV    (1.0f / 32768.0f)
#define LDT    40   // gemm LDS row stride (ushorts): 80B, 16B-aligned
#define NWG    256

typedef unsigned short ushort_t;
typedef __attribute__((ext_vector_type(8))) short bf16x8;
typedef __attribute__((ext_vector_type(4))) float f32x4;
typedef __attribute__((ext_vector_type(4))) unsigned int u32x4;

__device__ __forceinline__ ushort_t f2bf(float f) {
  unsigned u = __builtin_bit_cast(unsigned, f);
  u += 0x7fffu + ((u >> 16) & 1u);          // RNE
  return (ushort_t)(u >> 16);
}
__device__ __forceinline__ float bf2f(ushort_t h) {
  return __builtin_bit_cast(float, (unsigned)h << 16);
}

// ---- MALL-coherent ops (sc0 sc1): proven exchange scope ----
__device__ __forceinline__ u32x4 ld_mall_x4(const void* p) {
  u32x4 r;
  asm volatile("global_load_dwordx4 %0, %1, off sc0 sc1"
               : "=v"(r) : "v"(p) : "memory");
  return r;
}
__device__ __forceinline__ void st_mall_u32(unsigned* p, unsigned v) {
  asm volatile("global_store_dword %0, %1, off sc0 sc1"
               :: "v"(p), "v"(v) : "memory");
}
// ---- ordinary cached ops, ordered volatile asm ----
__device__ __forceinline__ int ldg_sshort(const short* p) {
  int r;
  asm volatile("global_load_sshort %0, %1, off" : "=v"(r) : "v"(p) : "memory");
  return r;
}
__device__ __forceinline__ int ldg_s32(const int* p) {
  int r;
  asm volatile("global_load_dword %0, %1, off" : "=v"(r) : "v"(p) : "memory");
  return r;
}
__device__ __forceinline__ void stg_f32(float* p, float v) {
  asm volatile("global_store_dword %0, %1, off" :: "v"(p), "v"(v) : "memory");
}
#define WAITV0 do { asm volatile("s_waitcnt vmcnt(0)" ::: "memory"); \
                    __builtin_amdgcn_sched_barrier(0); } while (0)

// ---------------- Phase 1: gathered GEMM, 128x128 tile, BK=32, 4 waves,
// 1-term plain bf16 (r16-proven, absmax-neutral).
__global__ __launch_bounds__(256) void gemm_xp(
    const float* __restrict__ emb, const float* __restrict__ Wx,
    const int* __restrict__ x, const float* __restrict__ b_i,
    short* __restrict__ xp)
{
  __shared__ ushort_t aH[128 * LDT];
  __shared__ ushort_t bH[128 * LDT];
  const int tid = threadIdx.x, lane = tid & 63, w = tid >> 6;
  const int bx = blockIdx.x;
  const int nIdx = bx % 24, mIdx = bx / 24;
  const int m0 = mIdx * 128, n0 = nIdx * 128;

  const int aRow0 = tid >> 2, aRow1 = (tid + 256) >> 2, aKoct = tid & 3;
  const size_t aBase0 = (size_t)x[m0 + aRow0] * E_DIM + (size_t)aKoct * 8;
  const size_t aBase1 = (size_t)x[m0 + aRow1] * E_DIM + (size_t)aKoct * 8;
  const int bN = tid & 127, bKoct0 = tid >> 7;

  const int wr = (w >> 1) * 64, wc = (w & 1) * 64;
  f32x4 acc[4][4];
#pragma unroll
  for (int i = 0; i < 4; i++)
#pragma unroll
    for (int j = 0; j < 4; j++) acc[i][j] = (f32x4){0.f, 0.f, 0.f, 0.f};

  for (int k0 = 0; k0 < E_DIM; k0 += 32) {
    __syncthreads();
#pragma unroll
    for (int pp = 0; pp < 2; ++pp) {
      const float* src = emb + (pp ? aBase1 : aBase0) + k0;
      int row = pp ? aRow1 : aRow0;
      float4 v0 = *(const float4*)(src);
      float4 v1 = *(const float4*)(src + 4);
      float vv[8] = {v0.x, v0.y, v0.z, v0.w, v1.x, v1.y, v1.z, v1.w};
      bf16x8 oh;
#pragma unroll
      for (int j = 0; j < 8; ++j) oh[j] = (short)f2bf(vv[j]);
      *(bf16x8*)&aH[row * LDT + aKoct * 8] = oh;
    }
#pragma unroll
    for (int kk = 0; kk < 2; ++kk) {
      int koct = bKoct0 + 2 * kk;
      float vv[8];
#pragma unroll
      for (int e = 0; e < 8; ++e)
        vv[e] = Wx[(size_t)(k0 + koct * 8 + e) * G3 + n0 + bN];
      bf16x8 oh;
#pragma unroll
      for (int j = 0; j < 8; ++j) oh[j] = (short)f2bf(vv[j]);
      *(bf16x8*)&bH[bN * LDT + koct * 8] = oh;
    }
    __syncthreads();
    bf16x8 afH[4], bfH[4];
#pragma unroll
    for (int mi = 0; mi < 4; mi++) {
      int off = (wr + mi * 16 + (lane & 15)) * LDT + (lane >> 4) * 8;
      afH[mi] = *(const bf16x8*)&aH[off];
    }
#pragma unroll
    for (int ni = 0; ni < 4; ni++) {
      int off = (wc + ni * 16 + (lane & 15)) * LDT + (lane >> 4) * 8;
      bfH[ni] = *(const bf16x8*)&bH[off];
    }
#pragma unroll
    for (int mi = 0; mi < 4; mi++)
#pragma unroll
      for (int ni = 0; ni < 4; ni++)
        acc[mi][ni] = __builtin_amdgcn_mfma_f32_16x16x32_bf16(afH[mi], bfH[ni], acc[mi][ni], 0, 0, 0);
  }
#pragma unroll
  for (int ni = 0; ni < 4; ni++) {
    int col = n0 + wc + ni * 16 + (lane & 15);
    float bias = b_i[col];
#pragma unroll
    for (int mi = 0; mi < 4; mi++) {
      int rbase = m0 + wr + mi * 16 + (lane >> 4) * 4;
#pragma unroll
      for (int i = 0; i < 4; i++) {
        int m = rbase + i;
        int b = m >> 9, t = m & 511;
        float v = acc[mi][ni][i] + bias;
        int q = __float2int_rn(v * XP_SCALE);
        q = q > 32767 ? 32767 : (q < -32768 ? -32768 : q);
        xp[(size_t)(t * 64 + b) * G3 + col] = (short)q;
      }
    }
  }
}

// ---------------- Phase 0: pack hidden -> tagged h32 buf0 (tag 0);
// buf1 = sentinel tag 0xFFFF (never matches a want in [0,512]).
__global__ __launch_bounds__(256) void init_h(
    const float* __restrict__ hidden,
    unsigned* __restrict__ h32)
{
  const int i = blockIdx.x * 256 + threadIdx.x;
  if (i < BU) {
    int q = __float2int_rn(hidden[i] * H_SCALE);
    q = q > 32767 ? 32767 : (q < -32768 ? -32768 : q);
    h32[i] = (unsigned)(unsigned short)(short)q;      // tag 0 | h
    h32[BU + i] = 0xFFFF0000u;                        // sentinel
  }
}

// ---------------- Phase 2: persistent GRU scan, self-certifying h words.
// WG(bx): uj = bx&63 (u-tile of 16), bi = bx>>6 (batch-group of 16 rows).
// Wave w (0..7) owns K-seg [128w,128w+128). Verified MFMA layouts:
// A row=lane&15 k=(lane>>4)*8+j; B col=lane&15 same k; C row=(lane>>4)*4+i
// col=lane&15. h word = (tag<<16)|int16@2^15; consumers retry-load until
// all 32 tags/lane == t; producer stores are fire-and-forget. ONE
// syncthreads/step (part publish -> epi read); part[] double-buffered.
__global__ __launch_bounds__(512) void gru_scan(
    const float* __restrict__ hidden,  // [64][1024] f32 (hp init)
    const float* __restrict__ Wh,      // [1024][3072] f32
    const float* __restrict__ b_r,     // [3072]
    const short* __restrict__ xp,      // [T][64][3072] int16
    const int* __restrict__ x,         // [64][512]
    unsigned* __restrict__ h32,        // [2][64][1024] tagged words
    float* __restrict__ out)           // [64][512][1024] f32 + [64][1024] state
{
  __shared__ float part[2][8][3][64][4];   // [buf][kseg][gate][lane][e] 48KB
  const int tid  = threadIdx.x;
  const int lane = tid & 63;
  const int w    = tid >> 6;            // wave id = K-segment
  const int bx   = (int)blockIdx.x;
  const int uj   = bx & 63, bi = bx >> 6;
  const int u0   = uj * 16, b0 = bi * 16;
  const int c16  = lane & 15;           // fragment row/col-within-tile
  const int kg   = lane >> 4;           // k-group (x8)

  // ---- Wh fragments hi+lo, resident (built once, cached loads) ----
  bf16x8 BH[4][3], BL[4][3];
#pragma unroll
  for (int ks = 0; ks < 4; ++ks)
#pragma unroll
    for (int g = 0; g < 3; ++g) {
      bf16x8 bh, bl;
#pragma unroll
      for (int j = 0; j < 8; ++j) {
        int k = w * 128 + ks * 32 + kg * 8 + j;
        float v = Wh[(size_t)k * G3 + g * 1024 + u0 + c16];
        ushort_t hi = f2bf(v);
        bh[j] = (short)hi;
        bl[j] = (short)f2bf(v - bf2f(hi));
      }
      BH[ks][g] = bh;
      BL[ks][g] = bl;
    }

  // ---- epilogue ownership: waves 0-3 (tid<256): one (b,u) per thread ----
  const bool epi = (tid < 256);
  const int ebl = (tid >> 4) & 15, eul = tid & 15;
  const int eb = b0 + ebl, eu = u0 + eul;
  const int pl = (ebl >> 2) * 16 + eul, pe = ebl & 3;
  float brz = 0.f, brr = 0.f, brh = 0.f, hp = 0.f;
  if (epi) {
    brz = b_r[eu]; brr = b_r[1024 + eu]; brh = b_r[2048 + eu];
    hp  = hidden[(size_t)eb * U_DIM + eu];
  }

  asm volatile("s_waitcnt vmcnt(0) lgkmcnt(0)" ::: "memory");

  // prologue: prefetch xq for t=0 (retired by the retry loop's WAITV0).
  int xq0 = 0, xq1 = 0, xq2 = 0, xtok = 0;
  if (epi) {
    xq0 = ldg_sshort(xp + (size_t)eb * G3 + eu);
    xq1 = ldg_sshort(xp + (size_t)eb * G3 + 1024 + eu);
    xq2 = ldg_sshort(xp + (size_t)eb * G3 + 2048 + eu);
    xtok = ldg_s32(x + eb * T_LEN + 0);
  }

  unsigned spins = 0;            // global retry budget: bail -> visible fail
  for (int t = 0; t < T_LEN; ++t) {
    const unsigned* __restrict__ rP = h32 + (size_t)(t & 1) * BU;
    unsigned* __restrict__ wP       = h32 + (size_t)((t + 1) & 1) * BU;

    // A rows = group's 16 h-rows; row c16, k-base w*128 + kg*8 (u32 words)
    const unsigned* pP = rP + (size_t)(b0 + c16) * U_DIM + w * 128 + kg * 8;
    const unsigned want = (unsigned)t << 16;

    // ---- speculative A-load + tag check (the load IS the poll) ----
    u32x4 Q0, Q1, Q2, Q3, Q4, Q5, Q6, Q7;
    for (;;) {
      Q0 = ld_mall_x4(pP + 0);   Q1 = ld_mall_x4(pP + 4);
      Q2 = ld_mall_x4(pP + 32);  Q3 = ld_mall_x4(pP + 36);
      Q4 = ld_mall_x4(pP + 64);  Q5 = ld_mall_x4(pP + 68);
      Q6 = ld_mall_x4(pP + 96);  Q7 = ld_mall_x4(pP + 100);
      WAITV0;
      unsigned bad;
#define CK(Q_) ((Q_[0] ^ want) | (Q_[1] ^ want) | (Q_[2] ^ want) | (Q_[3] ^ want))
      bad = (CK(Q0) | CK(Q1) | CK(Q2) | CK(Q3) |
             CK(Q4) | CK(Q5) | CK(Q6) | CK(Q7)) & 0xFFFF0000u;
#undef CK
      if (__ballot(bad == 0u) == ~0ull) break;
      if (++spins > (1u << 20)) break;   // bail visibly, never hang
      if (spins > 2) __builtin_amdgcn_s_sleep(1);
    }

    f32x4 acc[3];
#pragma unroll
    for (int g = 0; g < 3; ++g) acc[g] = (f32x4){0.f, 0.f, 0.f, 0.f};

    // unpack tagged words -> EXACT split bf16 (int16@2^15), then 3-term MFMA
#define UNPK(QA_, QB_, AH_, AL_) \
    { \
      _Pragma("unroll") \
      for (int j = 0; j < 4; ++j) { \
        float v = (float)(short)(QA_[j] & 0xffffu) * H_INV; \
        ushort_t hi = f2bf(v); \
        AH_[j] = (short)hi; \
        AL_[j] = (short)f2bf(v - bf2f(hi)); \
      } \
      _Pragma("unroll") \
      for (int j = 0; j < 4; ++j) { \
        float v = (float)(short)(QB_[j] & 0xffffu) * H_INV; \
        ushort_t hi = f2bf(v); \
        AH_[4 + j] = (short)hi; \
        AL_[4 + j] = (short)f2bf(v - bf2f(hi)); \
      } \
    }
#define COMP(AH_, AL_, ks_) \
    _Pragma("unroll") \
    for (int g = 0; g < 3; ++g) { \
      acc[g] = __builtin_amdgcn_mfma_f32_16x16x32_bf16(AH_, BH[ks_][g], acc[g], 0, 0, 0); \
      acc[g] = __builtin_amdgcn_mfma_f32_16x16x32_bf16(AH_, BL[ks_][g], acc[g], 0, 0, 0); \
      acc[g] = __builtin_amdgcn_mfma_f32_16x16x32_bf16(AL_, BH[ks_][g], acc[g], 0, 0, 0); \
    }
    {
      bf16x8 AH, AL;
      UNPK(Q0, Q1, AH, AL)
      COMP(AH, AL, 0)
      UNPK(Q2, Q3, AH, AL)
      COMP(AH, AL, 1)
      UNPK(Q4, Q5, AH, AL)
      COMP(AH, AL, 2)
      UNPK(Q6, Q7, AH, AL)
      COMP(AH, AL, 3)
    }
#undef UNPK
#undef COMP

    // ---- partials -> LDS (double-buffered), lane-major b128 writes ----
#pragma unroll
    for (int g = 0; g < 3; ++g)
      *(f32x4*)&part[t & 1][w][g][lane][0] = acc[g];

    __syncthreads();   // the ONE sync: parts visible for epi read

    if (epi) {
      float sz = 0.f, sr = 0.f, sh = 0.f;
#pragma unroll
      for (int s = 0; s < 8; ++s) {
        sz += part[t & 1][s][0][pl][pe];
        sr += part[t & 1][s][1][pl][pe];
        sh += part[t & 1][s][2][pl][pe];
      }

      const float hz = sz + brz, hr = sr + brr, hhv = sh + brh;
      const float xz = (float)xq0 * XP_INV;
      const float xr = (float)xq1 * XP_INV;
      const float xh = (float)xq2 * XP_INV;
      const float z = 1.f / (1.f + __expf(-(xz + hz)));
      const float r = 1.f / (1.f + __expf(-(xr + hr)));
      const float ca = xh + r * hhv;
      const float cand = 1.f - 2.f / (__expf(2.f * ca) + 1.f);   // tanh
      float hn = z * hp + (1.f - z) * cand;
      hn = (xtok != 0) ? hn : hp;
      hp = hn;

      // fire-and-forget publication: tagged h word (the flag IS the data)
      int q = __float2int_rn(hn * H_SCALE);
      q = q > 32767 ? 32767 : (q < -32768 ? -32768 : q);
      const unsigned word = ((unsigned)(t + 1) << 16) |
                            (unsigned)(unsigned short)(short)q;
      st_mall_u32(wP + (size_t)eb * U_DIM + eu, word);
      stg_f32(&out[((size_t)eb * T_LEN + t) * U_DIM + eu], hn);

      const int tp = (t < T_LEN - 1) ? t + 1 : t;
      xq0 = ldg_sshort(xp + ((size_t)tp * B_SZ + eb) * G3 + eu);
      xq1 = ldg_sshort(xp + ((size_t)tp * B_SZ + eb) * G3 + 1024 + eu);
      xq2 = ldg_sshort(xp + ((size_t)tp * B_SZ + eb) * G3 + 2048 + eu);
      xtok = ldg_s32(x + eb * T_LEN + tp);
    }
    __builtin_amdgcn_sched_barrier(0);
  }

  // final state = hp (exact register carry)
  if (epi)
    out[(size_t)B_SZ * T_LEN * U_DIM + (size_t)eb * U_DIM + eu] = hp;
}

// ---------------- launch
extern "C" void kernel_launch(void* const* d_in, const int* in_sizes, int n_in,
                              void* d_out, int out_size, void* d_ws, size_t ws_size,
                              hipStream_t stream) {
  const int*   x      = (const int*)  d_in[0];
  const float* hidden = (const float*)d_in[1];
  const float* emb    = (const float*)d_in[2];
  const float* Wx     = (const float*)d_in[3];
  const float* Wh     = (const float*)d_in[4];
  const float* b_i    = (const float*)d_in[5];
  const float* b_r    = (const float*)d_in[6];
  float* out = (float*)d_out;

  const size_t XP_B = (size_t)T_LEN * B_SZ * G3 * 2;   // 201,326,592 (int16)
  const size_t NEED = XP_B + 8 * (size_t)BU;           // + h32 x2
  if (ws_size < NEED) return;

  short*    xp  = (short*)d_ws;
  unsigned* h32 = (unsigned*)((char*)d_ws + XP_B);     // [2][BU] tagged words

  init_h<<<BU / 256, 256, 0, stream>>>(hidden, h32);
  gemm_xp<<<(32768 / 128) * (G3 / 128), 256, 0, stream>>>(emb, Wx, x, b_i, xp);
  gru_scan<<<NWG, 512, 0, stream>>>(hidden, Wh, b_r, xp, x, h32, out);
}

// Round 14
// 2637.384 us; speedup vs baseline: 1.4164x; 1.4164x over previous
//
#include <hip/hip_runtime.h>
#include <stdint.h>

// GRU encoder: B=64 T=512 U=E=1024 V=32000, gates z|r|h, reset_after=True.
// Round-20 = r16 REVERT (best verified: 2634us total / 2240us scan).
// r19 post-mortem: self-certifying tags = per-wave polling via full A-reloads
// (FETCH x1.8, xq overlap lost) -> -47%. Protocol search is exhausted:
//   payload bytes (r11 neutral) | arrival (r15 +) | detect+prepoll (r16 +)
//   per-wave dataflow (r14 -) | paired chains (r13 -) | 2WG/CU (r12 NaN)
//   XCD-local (r17/r18 fail) | tagged data (r19 -).
// r16 structure:
//   Phase 0: init_h  — quantize hidden -> int16 h-plane, zero 4096 flags.
//   Phase 1: gemm_xp — 1-term bf16 gather GEMM (absmax-neutral, proven).
//   Phase 2: gru_scan — 256 WGs x 512 thr; int16 h @2^15 exchange (exact
//     split-bf16 unpack, 3-term ladder); parallel per-WG flag arrival
//     (own 64B line, no RMW); single wave-0 poller + wave-7 bounded
//     pre-poll; h16-first store order + WAITV(5) drain; counted-vmcnt
//     A-load ladder; lane-major part[] (conflict-free b128).
// ws: xp 201.33MB | h16 2x128KB | flags 16KB = 201.60MB.

#define B_SZ   64
#define T_LEN  512
#define U_DIM  1024
#define E_DIM  1024
#define G3     3072
#define BU     (B_SZ * U_DIM)
#define XP_SCALE 131072.0f
#define XP_INV   (1.0f / 131072.0f)
#define H_SCALE  32768.0f
#define H_INV    (1.0f / 32768.0f)
#define LDT    40   // gemm LDS row stride (ushorts): 80B, 16B-aligned
#define NWG    256

typedef unsigned short ushort_t;
typedef __attribute__((ext_vector_type(8))) short bf16x8;
typedef __attribute__((ext_vector_type(4))) float f32x4;

__device__ __forceinline__ ushort_t f2bf(float f) {
  unsigned u = __builtin_bit_cast(unsigned, f);
  u += 0x7fffu + ((u >> 16) & 1u);          // RNE
  return (ushort_t)(u >> 16);
}
__device__ __forceinline__ float bf2f(ushort_t h) {
  return __builtin_bit_cast(float, (unsigned)h << 16);
}

// ---- coherent (MALL-point) memory ops: bypass L1+L2 via sc0 sc1 ----
__device__ __forceinline__ bf16x8 ldg_cohere_b128(const void* p) {
  bf16x8 r;
  asm volatile("global_load_dwordx4 %0, %1, off sc0 sc1"
               : "=v"(r) : "v"(p) : "memory");
  return r;
}
__device__ __forceinline__ void stg_cohere_u16(short* p, unsigned v) {
  asm volatile("global_store_short %0, %1, off sc0 sc1"
               :: "v"(p), "v"(v) : "memory");
}
__device__ __forceinline__ void stg_cohere_u32(unsigned* p, unsigned v) {
  asm volatile("global_store_dword %0, %1, off sc0 sc1"
               :: "v"(p), "v"(v) : "memory");
}
__device__ __forceinline__ unsigned ldg_cohere_u32(const unsigned* p) {
  unsigned r;
  asm volatile("global_load_dword %0, %1, off sc0 sc1\n\ts_waitcnt vmcnt(0)"
               : "=v"(r) : "v"(p) : "memory");
  return r;
}
// ---- ordinary cached ops, but as ordered volatile asm (vmcnt counting) ----
__device__ __forceinline__ int ldg_sshort(const short* p) {
  int r;
  asm volatile("global_load_sshort %0, %1, off" : "=v"(r) : "v"(p) : "memory");
  return r;
}
__device__ __forceinline__ int ldg_s32(const int* p) {
  int r;
  asm volatile("global_load_dword %0, %1, off" : "=v"(r) : "v"(p) : "memory");
  return r;
}
__device__ __forceinline__ void stg_u32(float* p, float v) {
  asm volatile("global_store_dword %0, %1, off" :: "v"(p), "v"(v) : "memory");
}
#define WAITV(n) do { asm volatile("s_waitcnt vmcnt(" #n ")" ::: "memory"); \
                      __builtin_amdgcn_sched_barrier(0); } while (0)

// ---------------- Phase 1: gathered GEMM, 128x128 tile, BK=32, 4 waves,
// 1-term plain bf16 (hi-only staging), 20.5KB static LDS.
__global__ __launch_bounds__(256) void gemm_xp(
    const float* __restrict__ emb,    // [V][1024] f32 (gathered rows)
    const float* __restrict__ Wx,     // [1024][3072] f32
    const int* __restrict__ x,        // [B*T] (m = b*T+t)
    const float* __restrict__ b_i,    // [3072]
    short* __restrict__ xp)           // [T][B][3072] int16 (x 2^17)
{
  __shared__ ushort_t aH[128 * LDT];
  __shared__ ushort_t bH[128 * LDT];
  const int tid = threadIdx.x, lane = tid & 63, w = tid >> 6;
  const int bx = blockIdx.x;
  const int nIdx = bx % 24, mIdx = bx / 24;
  const int m0 = mIdx * 128, n0 = nIdx * 128;

  const int aRow0 = tid >> 2, aRow1 = (tid + 256) >> 2, aKoct = tid & 3;
  const size_t aBase0 = (size_t)x[m0 + aRow0] * E_DIM + (size_t)aKoct * 8;
  const size_t aBase1 = (size_t)x[m0 + aRow1] * E_DIM + (size_t)aKoct * 8;
  const int bN = tid & 127, bKoct0 = tid >> 7;

  const int wr = (w >> 1) * 64, wc = (w & 1) * 64;
  f32x4 acc[4][4];
#pragma unroll
  for (int i = 0; i < 4; i++)
#pragma unroll
    for (int j = 0; j < 4; j++) acc[i][j] = (f32x4){0.f, 0.f, 0.f, 0.f};

  for (int k0 = 0; k0 < E_DIM; k0 += 32) {
    __syncthreads();
#pragma unroll
    for (int pp = 0; pp < 2; ++pp) {
      const float* src = emb + (pp ? aBase1 : aBase0) + k0;
      int row = pp ? aRow1 : aRow0;
      float4 v0 = *(const float4*)(src);
      float4 v1 = *(const float4*)(src + 4);
      float vv[8] = {v0.x, v0.y, v0.z, v0.w, v1.x, v1.y, v1.z, v1.w};
      bf16x8 oh;
#pragma unroll
      for (int j = 0; j < 8; ++j) oh[j] = (short)f2bf(vv[j]);
      *(bf16x8*)&aH[row * LDT + aKoct * 8] = oh;
    }
#pragma unroll
    for (int kk = 0; kk < 2; ++kk) {
      int koct = bKoct0 + 2 * kk;
      float vv[8];
#pragma unroll
      for (int e = 0; e < 8; ++e)
        vv[e] = Wx[(size_t)(k0 + koct * 8 + e) * G3 + n0 + bN];
      bf16x8 oh;
#pragma unroll
      for (int j = 0; j < 8; ++j) oh[j] = (short)f2bf(vv[j]);
      *(bf16x8*)&bH[bN * LDT + koct * 8] = oh;
    }
    __syncthreads();
    bf16x8 afH[4], bfH[4];
#pragma unroll
    for (int mi = 0; mi < 4; mi++) {
      int off = (wr + mi * 16 + (lane & 15)) * LDT + (lane >> 4) * 8;
      afH[mi] = *(const bf16x8*)&aH[off];
    }
#pragma unroll
    for (int ni = 0; ni < 4; ni++) {
      int off = (wc + ni * 16 + (lane & 15)) * LDT + (lane >> 4) * 8;
      bfH[ni] = *(const bf16x8*)&bH[off];
    }
#pragma unroll
    for (int mi = 0; mi < 4; mi++)
#pragma unroll
      for (int ni = 0; ni < 4; ni++)
        acc[mi][ni] = __builtin_amdgcn_mfma_f32_16x16x32_bf16(afH[mi], bfH[ni], acc[mi][ni], 0, 0, 0);
  }
#pragma unroll
  for (int ni = 0; ni < 4; ni++) {
    int col = n0 + wc + ni * 16 + (lane & 15);
    float bias = b_i[col];
#pragma unroll
    for (int mi = 0; mi < 4; mi++) {
      int rbase = m0 + wr + mi * 16 + (lane >> 4) * 4;
#pragma unroll
      for (int i = 0; i < 4; i++) {
        int m = rbase + i;
        int b = m >> 9, t = m & 511;
        float v = acc[mi][ni][i] + bias;
        int q = __float2int_rn(v * XP_SCALE);
        q = q > 32767 ? 32767 : (q < -32768 ? -32768 : q);
        xp[(size_t)(t * 64 + b) * G3 + col] = (short)q;
      }
    }
  }
}

// ---------------- Phase 0: quantize hidden -> int16 h-plane (buffer 0),
// zero the 4096 flag words (4 groups x 64 flags x 16-dword stride).
__global__ __launch_bounds__(256) void init_h(
    const float* __restrict__ hidden,
    short* __restrict__ h16,
    unsigned* __restrict__ flags)
{
  const int i = blockIdx.x * 256 + threadIdx.x;
  if (blockIdx.x < 16) flags[blockIdx.x * 256 + threadIdx.x] = 0u;
  if (i < BU) {
    int q = __float2int_rn(hidden[i] * H_SCALE);
    q = q > 32767 ? 32767 : (q < -32768 ? -32768 : q);
    h16[i] = (short)q;
  }
}

// ---------------- Phase 2: persistent GRU scan, parallel-flag barrier +
// wave-7 pre-poll shortcut. WG(bx): uj = bx&63 (u-tile of 16), bi = bx>>6
// (batch-group of 16 rows). Wave w (0..7) owns K-segment [128w,128w+128).
// Verified MFMA layouts: A row=lane&15 k=(lane>>4)*8+j; B col=lane&15 same
// k; C row=(lane>>4)*4+i col=lane&15. h exchanged as int16 @2^15 (one
// plane, double-buffered); unpacked to EXACT split-bf16 in VALU.
// Barrier: arrival = tid0 plain sc0sc1 store to own 64B-padded flag (after
// sync(1) reads-consumed + WAITV h16-drained + sync(2)); detection = wave-0
// 64-lane flag read (skipped when wave-7's bounded pre-poll already saw all
// flags >= t during the epi window), s_sleep(1), syncthreads release.
__global__ __launch_bounds__(512) void gru_scan(
    const float* __restrict__ hidden,  // [64][1024] f32 (hp init)
    const float* __restrict__ Wh,      // [1024][3072] f32
    const float* __restrict__ b_r,     // [3072]
    const short* __restrict__ xp,      // [T][64][3072] int16
    const int* __restrict__ x,         // [64][512]
    short* __restrict__ h16,           // [2][64][1024] int16 @2^15
    unsigned* __restrict__ flags,      // [4][64][16] u32 (flag per 64B line)
    float* __restrict__ out)           // [64][512][1024] f32 + [64][1024] state
{
  __shared__ float part[8][3][64][4];   // [kseg][gate][lane][elem] 24KB
  __shared__ unsigned ready;            // wave-7 pre-poll verdict
  const int tid  = threadIdx.x;
  const int lane = tid & 63;
  const int w    = tid >> 6;            // wave id = K-segment
  const int bx   = (int)blockIdx.x;
  const int uj   = bx & 63, bi = bx >> 6;
  const int u0   = uj * 16, b0 = bi * 16;
  const int c16  = lane & 15;           // fragment row/col-within-tile
  const int kg   = lane >> 4;           // k-group (x8)
  unsigned* gflags = flags + bi * 1024;         // this group's 64 flag lines
  const unsigned* pollp = gflags + lane * 16;   // poller lane -> one flag

  // ---- Wh fragments resident in registers (built once, cached loads) ----
  bf16x8 BH[4][3], BL[4][3];
#pragma unroll
  for (int ks = 0; ks < 4; ++ks)
#pragma unroll
    for (int g = 0; g < 3; ++g) {
      bf16x8 bh, bl;
#pragma unroll
      for (int j = 0; j < 8; ++j) {
        int k = w * 128 + ks * 32 + kg * 8 + j;
        float v = Wh[(size_t)k * G3 + g * 1024 + u0 + c16];
        ushort_t hi = f2bf(v);
        bh[j] = (short)hi;
        bl[j] = (short)f2bf(v - bf2f(hi));
      }
      BH[ks][g] = bh;
      BL[ks][g] = bl;
    }

  // ---- epilogue ownership: waves 0-3 (tid<256): one (b,u) per thread ----
  const bool epi = (tid < 256);
  const int ebl = (tid >> 4) & 15, eul = tid & 15;
  const int eb = b0 + ebl, eu = u0 + eul;
  float brz = 0.f, brr = 0.f, brh = 0.f, hp = 0.f;
  if (epi) {
    brz = b_r[eu]; brr = b_r[1024 + eu]; brh = b_r[2048 + eu];
    hp  = hidden[(size_t)eb * U_DIM + eu];
  }

  // drain everything before entering the counted-vmcnt regime
  asm volatile("s_waitcnt vmcnt(0) lgkmcnt(0)" ::: "memory");

  // prologue: prefetch xq for t=0 (epi waves carry 4 extra in-flight loads;
  // every WAITV below is FIFO oldest-first and correct for both wave classes;
  // wave-0/7 poll vmcnt(0) merely retires their older ops early).
  int xq0 = 0, xq1 = 0, xq2 = 0, xtok = 0;
  if (epi) {
    xq0 = ldg_sshort(xp + (size_t)eb * G3 + eu);
    xq1 = ldg_sshort(xp + (size_t)eb * G3 + 1024 + eu);
    xq2 = ldg_sshort(xp + (size_t)eb * G3 + 2048 + eu);
    xtok = ldg_s32(x + eb * T_LEN + 0);
  }

  unsigned spins = 0;            // global spin budget: deadlock bails visibly
  for (int t = 0; t < T_LEN; ++t) {
    const short* __restrict__ rP = h16 + (size_t)(t & 1) * BU;
    short* __restrict__ wP       = h16 + (size_t)((t + 1) & 1) * BU;

    // ---- barrier wait: all 64 group flags >= t; skipped if wave-7's
    // pre-poll already confirmed during last step's epi window ----
    if (t > 0) {
      if (w == 0) {
        if (ready == 0u) {
          const unsigned tgt = (unsigned)t;
          while (spins < (1u << 22)) {
            unsigned f = ldg_cohere_u32(pollp);   // 64 lanes -> 64 flags
            if (__ballot(f >= tgt) == ~0ull) break;
            __builtin_amdgcn_s_sleep(1);
            ++spins;
          }
        }
      }
      __syncthreads();   // release: h(t) fully MALL-visible
    }

    // A rows = this group's 16 h-rows; row c16, k-base w*128 + kg*8
    const short* pP = rP + (size_t)(b0 + c16) * U_DIM + w * 128 + kg * 8;

    f32x4 acc[3];
#pragma unroll
    for (int g = 0; g < 3; ++g) acc[g] = (f32x4){0.f, 0.f, 0.f, 0.f};

    // issue all 4 packed A-loads upfront; FIFO waits (epi waves carry 5
    // older ops [out,xq x4] in steady state; oldest retire first -> counts
    // valid for every wave class):
    //   WAITV(3)->P0 done, WAITV(2)->P1, WAITV(1)->P2, WAITV(0)->P3.
    bf16x8 P0, P1, P2, P3;
    P0 = ldg_cohere_b128(pP + 0 * 32);
    P1 = ldg_cohere_b128(pP + 1 * 32);
    P2 = ldg_cohere_b128(pP + 2 * 32);
    P3 = ldg_cohere_b128(pP + 3 * 32);

    // unpack int16 -> EXACT split bf16 (hi 8 mant bits + lo rest), then MFMA
#define UNPCK(P_, AH_, AL_) \
    { \
      _Pragma("unroll") \
      for (int j = 0; j < 8; ++j) { \
        float v = (float)(short)P_[j] * H_INV; \
        ushort_t hi = f2bf(v); \
        AH_[j] = (short)hi; \
        AL_[j] = (short)f2bf(v - bf2f(hi)); \
      } \
    }
#define COMP(AH_, AL_, ks_) \
    _Pragma("unroll") \
    for (int g = 0; g < 3; ++g) { \
      acc[g] = __builtin_amdgcn_mfma_f32_16x16x32_bf16(AH_, BH[ks_][g], acc[g], 0, 0, 0); \
      acc[g] = __builtin_amdgcn_mfma_f32_16x16x32_bf16(AH_, BL[ks_][g], acc[g], 0, 0, 0); \
      acc[g] = __builtin_amdgcn_mfma_f32_16x16x32_bf16(AL_, BH[ks_][g], acc[g], 0, 0, 0); \
    }
    bf16x8 AH, AL;
    WAITV(3);
    UNPCK(P0, AH, AL)
    COMP(AH, AL, 0)
    WAITV(2);
    UNPCK(P1, AH, AL)
    COMP(AH, AL, 1)
    WAITV(1);
    UNPCK(P2, AH, AL)
    COMP(AH, AL, 2)
    WAITV(0);
    UNPCK(P3, AH, AL)
    COMP(AH, AL, 3)
#undef UNPCK
#undef COMP

    // ---- K-segment partials -> LDS, lane-major: contiguous b128 writes ----
#pragma unroll
    for (int g = 0; g < 3; ++g)
      *(f32x4*)&part[w][g][lane][0] = acc[g];

    __syncthreads();   // (1) parts visible; ALL waves' A-reads consumed

    if (epi) {
      // C elem: row ebl col eul -> producer lane (ebl>>2)*16+eul, elem ebl&3
      const int pl = (ebl >> 2) * 16 + eul, pe = ebl & 3;
      float sz = 0.f, sr = 0.f, sh = 0.f;
#pragma unroll
      for (int s = 0; s < 8; ++s) {
        sz += part[s][0][pl][pe];
        sr += part[s][1][pl][pe];
        sh += part[s][2][pl][pe];
      }

      // ---- fused gate epilogue (xq values prefetched last iteration) ----
      const float hz = sz + brz, hr = sr + brr, hhv = sh + brh;
      const float xz = (float)xq0 * XP_INV;
      const float xr = (float)xq1 * XP_INV;
      const float xh = (float)xq2 * XP_INV;
      const float z = 1.f / (1.f + __expf(-(xz + hz)));
      const float r = 1.f / (1.f + __expf(-(xr + hr)));
      const float ca = xh + r * hhv;
      const float cand = 1.f - 2.f / (__expf(2.f * ca) + 1.f);   // tanh
      float hn = z * hp + (1.f - z) * cand;
      hn = (xtok != 0) ? hn : hp;
      hp = hn;

      // ordered stores: h16 FIRST (the flag gate), then out, then 4 xq
      // prefetches; WAITV(5) drains exactly [h16] (oldest) -> h visible at
      // MALL; out + xq still flying (out is stream-ordered, host-only).
      int q = __float2int_rn(hn * H_SCALE);
      q = q > 32767 ? 32767 : (q < -32768 ? -32768 : q);
      stg_cohere_u16(wP + (size_t)eb * U_DIM + eu, (unsigned)q);
      stg_u32(&out[((size_t)eb * T_LEN + t) * U_DIM + eu], hn);

      const int tp = (t < T_LEN - 1) ? t + 1 : t;
      xq0 = ldg_sshort(xp + ((size_t)tp * B_SZ + eb) * G3 + eu);
      xq1 = ldg_sshort(xp + ((size_t)tp * B_SZ + eb) * G3 + 1024 + eu);
      xq2 = ldg_sshort(xp + ((size_t)tp * B_SZ + eb) * G3 + 2048 + eu);
      xtok = ldg_s32(x + eb * T_LEN + tp);
      WAITV(5);
    } else if (w == 7) {
      // ---- bounded pre-poll for step t+1 during the epi window (costs at
      // most ~2 MALL RTs, < epi epilogue length -> never delays our flag).
      const unsigned tgt2 = (unsigned)(t + 1);
      unsigned ok = 0;
#pragma unroll
      for (int it = 0; it < 2; ++it) {
        if (!ok) {
          unsigned f = ldg_cohere_u32(pollp);
          if (__ballot(f >= tgt2) == ~0ull) ok = 1u;
        }
      }
      if (lane == 0) ready = ok;
    }

    __syncthreads();   // (2) epi h16 drained; whole WG done with step t
    if (tid == 0)
      stg_cohere_u32(gflags + uj * 16, (unsigned)(t + 1));  // own line, no RMW
    __builtin_amdgcn_sched_barrier(0);
  }

  // final state = hp (exact register carry)
  if (epi)
    out[(size_t)B_SZ * T_LEN * U_DIM + (size_t)eb * U_DIM + eu] = hp;
}

// ---------------- launch
extern "C" void kernel_launch(void* const* d_in, const int* in_sizes, int n_in,
                              void* d_out, int out_size, void* d_ws, size_t ws_size,
                              hipStream_t stream) {
  const int*   x      = (const int*)  d_in[0];
  const float* hidden = (const float*)d_in[1];
  const float* emb    = (const float*)d_in[2];
  const float* Wx     = (const float*)d_in[3];
  const float* Wh     = (const float*)d_in[4];
  const float* b_i    = (const float*)d_in[5];
  const float* b_r    = (const float*)d_in[6];
  float* out = (float*)d_out;

  const size_t XP_B = (size_t)T_LEN * B_SZ * G3 * 2;   // 201,326,592 (int16)
  const size_t NEED = XP_B + 4 * (size_t)BU + 16384;   // + h16 x2 + flags
  if (ws_size < NEED) return;

  short*    xp    = (short*)d_ws;
  short*    h16   = (short*)((char*)d_ws + XP_B);      // [2][BU] int16
  unsigned* flags = (unsigned*)(h16 + 2 * (size_t)BU); // [4][64][16] u32

  init_h<<<BU / 256, 256, 0, stream>>>(hidden, h16, flags);
  gemm_xp<<<(32768 / 128) * (G3 / 128), 256, 0, stream>>>(emb, Wx, x, b_i, xp);
  gru_scan<<<NWG, 512, 0, stream>>>(hidden, Wh, b_r, xp, x, h16, flags, out);
}